// Round 3
// baseline (121.682 us; speedup 1.0000x reference)
//
#include <hip/hip_runtime.h>

constexpr int D   = 128;
constexpr int NEG = 5;

__device__ __forceinline__ float softplus_fast(float z) {
    // softplus(z) = max(z,0) + ln2 * log2(1 + 2^(-|z|*log2e)); hw v_exp/v_log
    float t = __builtin_amdgcn_exp2f(-fabsf(z) * 1.44269504f);
    return fmaxf(z, 0.0f) + 0.69314718f * __builtin_amdgcn_logf(1.0f + t);
}

__global__ void __launch_bounds__(256, 8)
sgns_loss_kernel(const float* __restrict__ emb,
                 const int*   __restrict__ centers,
                 const int*   __restrict__ contexts,
                 const int*   __restrict__ negs,
                 float* __restrict__ out,
                 int P, float invP) {
    __shared__ float bsum;
    if (threadIdx.x == 0) bsum = 0.0f;
    __syncthreads();

    const int lane = threadIdx.x & 63;
    const int sub  = lane & 31;                                   // 32 lanes per pair
    const int gid  = (int)((blockIdx.x * blockDim.x + threadIdx.x) >> 5);
    const int ngrp = (int)((gridDim.x * blockDim.x) >> 5);

    float local = 0.0f;

    int p = gid;
    int ic = 0, io = 0, i0 = 0, i1 = 0, i2 = 0, i3 = 0, i4 = 0;
    if (p < P) {
        ic = centers[p];  io = contexts[p];
        const int* nb = negs + (size_t)p * NEG;
        i0 = nb[0]; i1 = nb[1]; i2 = nb[2]; i3 = nb[3]; i4 = nb[4];
    }

    while (p < P) {
        // issue all 7 row loads (one float4 per lane = whole 512B row per group)
        const float4 v  = ((const float4*)(emb + (size_t)ic * D))[sub];
        const float4 c  = ((const float4*)(emb + (size_t)io * D))[sub];
        const float4 n0 = ((const float4*)(emb + (size_t)i0 * D))[sub];
        const float4 n1 = ((const float4*)(emb + (size_t)i1 * D))[sub];
        const float4 n2 = ((const float4*)(emb + (size_t)i2 * D))[sub];
        const float4 n3 = ((const float4*)(emb + (size_t)i3 * D))[sub];
        const float4 n4 = ((const float4*)(emb + (size_t)i4 * D))[sub];

        // prefetch next iteration's indices while rows are in flight
        const int pn = p + ngrp;
        if (pn < P) {
            ic = centers[pn];  io = contexts[pn];
            const int* nb = negs + (size_t)pn * NEG;
            i0 = nb[0]; i1 = nb[1]; i2 = nb[2]; i3 = nb[3]; i4 = nb[4];
        }

        float a0 = v.x*c.x  + v.y*c.y  + v.z*c.z  + v.w*c.w;
        float a1 = v.x*n0.x + v.y*n0.y + v.z*n0.z + v.w*n0.w;
        float a2 = v.x*n1.x + v.y*n1.y + v.z*n1.z + v.w*n1.w;
        float a3 = v.x*n2.x + v.y*n2.y + v.z*n2.z + v.w*n2.w;
        float a4 = v.x*n3.x + v.y*n3.y + v.z*n3.z + v.w*n3.w;
        float a5 = v.x*n4.x + v.y*n4.y + v.z*n4.z + v.w*n4.w;

        // 5-stage butterfly within each 32-lane half
#pragma unroll
        for (int off = 1; off < 32; off <<= 1) {
            a0 += __shfl_xor(a0, off, 64);
            a1 += __shfl_xor(a1, off, 64);
            a2 += __shfl_xor(a2, off, 64);
            a3 += __shfl_xor(a3, off, 64);
            a4 += __shfl_xor(a4, off, 64);
            a5 += __shfl_xor(a5, off, 64);
        }

        float loss = softplus_fast(-a0);   // -log_sigmoid(+dot)
        loss += softplus_fast(a1);         // -log_sigmoid(-dot) = softplus(dot)
        loss += softplus_fast(a2);
        loss += softplus_fast(a3);
        loss += softplus_fast(a4);
        loss += softplus_fast(a5);
        if (sub == 0) local += loss;

        p = pn;
    }

    // wave-level reduce (only sub==0 lanes hold nonzero)
#pragma unroll
    for (int off = 1; off < 64; off <<= 1)
        local += __shfl_xor(local, off, 64);
    if (lane == 0 && local != 0.0f) atomicAdd(&bsum, local * invP);
    __syncthreads();
    if (threadIdx.x == 0) atomicAdd(out, bsum);
}

extern "C" void kernel_launch(void* const* d_in, const int* in_sizes, int n_in,
                              void* d_out, int out_size, void* d_ws, size_t ws_size,
                              hipStream_t stream) {
    const float* emb      = (const float*)d_in[0];
    const int*   centers  = (const int*)d_in[1];
    const int*   contexts = (const int*)d_in[2];
    const int*   negs     = (const int*)d_in[3];
    float*       out      = (float*)d_out;

    const int P = in_sizes[1];
    const float invP = 1.0f / (float)P;

    hipMemsetAsync(d_out, 0, sizeof(float) * out_size, stream);

    const int block = 256;   // 8 pair-groups per block, 4 waves
    const int grid  = 2048;  // 8192 waves = full residency at 8 waves/SIMD
    sgns_loss_kernel<<<grid, block, 0, stream>>>(emb, centers, contexts, negs,
                                                 out, P, invP);
}

// Round 4
// 106.862 us; speedup vs baseline: 1.1387x; 1.1387x over previous
//
#include <hip/hip_runtime.h>

constexpr int D         = 128;
constexpr int NEG       = 5;
constexpr int GSIZE     = 8;                 // lanes per pair
constexpr int CHUNKS    = D / (4 * GSIZE);   // 4 float4 chunks per lane
constexpr int NBINS     = 1024;
constexpr int BINSTRIDE = 16;                // floats -> 64 B per bin (own cache line)

__device__ __forceinline__ float softplus_fast(float z) {
    // softplus(z) = max(z,0) + ln2 * log2(1 + 2^(-|z|*log2e)); hw v_exp/v_log
    float t = __builtin_amdgcn_exp2f(-fabsf(z) * 1.44269504f);
    return fmaxf(z, 0.0f) + 0.69314718f * __builtin_amdgcn_logf(1.0f + t);
}

__global__ void __launch_bounds__(256)
sgns_pair_kernel(const float* __restrict__ emb,
                 const int*   __restrict__ centers,
                 const int*   __restrict__ contexts,
                 const int*   __restrict__ negs,
                 float* __restrict__ bins,
                 int P, float invP) {
    const int sub = threadIdx.x & (GSIZE - 1);
    const int p   = blockIdx.x * (256 / GSIZE) + (threadIdx.x >> 3);

    float contrib = 0.0f;
    if (p < P) {
        const int  ic = centers[p];
        const int  io = contexts[p];
        const int* nb = negs + (size_t)p * NEG;
        const int  i0 = nb[0], i1 = nb[1], i2 = nb[2], i3 = nb[3], i4 = nb[4];

        const float4* vr  = (const float4*)(emb + (size_t)ic * D);
        const float4* cr  = (const float4*)(emb + (size_t)io * D);
        const float4* nr0 = (const float4*)(emb + (size_t)i0 * D);
        const float4* nr1 = (const float4*)(emb + (size_t)i1 * D);
        const float4* nr2 = (const float4*)(emb + (size_t)i2 * D);
        const float4* nr3 = (const float4*)(emb + (size_t)i3 * D);
        const float4* nr4 = (const float4*)(emb + (size_t)i4 * D);

        float a0 = 0.f, a1 = 0.f, a2 = 0.f, a3 = 0.f, a4 = 0.f, a5 = 0.f;
#pragma unroll
        for (int c = 0; c < CHUNKS; ++c) {
            const int idx = sub + GSIZE * c;
            const float4 v  = vr[idx];
            const float4 cc = cr[idx];
            const float4 n0 = nr0[idx];
            const float4 n1 = nr1[idx];
            const float4 n2 = nr2[idx];
            const float4 n3 = nr3[idx];
            const float4 n4 = nr4[idx];
            a0 += v.x*cc.x + v.y*cc.y + v.z*cc.z + v.w*cc.w;
            a1 += v.x*n0.x + v.y*n0.y + v.z*n0.z + v.w*n0.w;
            a2 += v.x*n1.x + v.y*n1.y + v.z*n1.z + v.w*n1.w;
            a3 += v.x*n2.x + v.y*n2.y + v.z*n2.z + v.w*n2.w;
            a4 += v.x*n3.x + v.y*n3.y + v.z*n3.z + v.w*n3.w;
            a5 += v.x*n4.x + v.y*n4.y + v.z*n4.z + v.w*n4.w;
        }

        // 3-stage butterfly within the 8-lane group
#pragma unroll
        for (int off = 1; off < GSIZE; off <<= 1) {
            a0 += __shfl_xor(a0, off, 64);
            a1 += __shfl_xor(a1, off, 64);
            a2 += __shfl_xor(a2, off, 64);
            a3 += __shfl_xor(a3, off, 64);
            a4 += __shfl_xor(a4, off, 64);
            a5 += __shfl_xor(a5, off, 64);
        }

        float loss = softplus_fast(-a0);   // -log_sigmoid(+dot)
        loss += softplus_fast(a1);         // -log_sigmoid(-dot) = softplus(dot)
        loss += softplus_fast(a2);
        loss += softplus_fast(a3);
        loss += softplus_fast(a4);
        loss += softplus_fast(a5);
        if (sub == 0) contrib = loss * invP;
    }

    // sum the 8 group-leader lanes (0,8,...,56) within each wave
#pragma unroll
    for (int off = GSIZE; off < 64; off <<= 1)
        contrib += __shfl_xor(contrib, off, 64);

    __shared__ float bsum;
    if (threadIdx.x == 0) bsum = 0.0f;
    __syncthreads();
    if ((threadIdx.x & 63) == 0) atomicAdd(&bsum, contrib);
    __syncthreads();
    if (threadIdx.x == 0)
        atomicAdd(&bins[(blockIdx.x & (NBINS - 1)) * BINSTRIDE], bsum);
}

__global__ void __launch_bounds__(256)
reduce_bins_kernel(const float* __restrict__ bins, float* __restrict__ out) {
    float s = 0.0f;
    for (int i = threadIdx.x; i < NBINS; i += 256)
        s += bins[i * BINSTRIDE];
#pragma unroll
    for (int off = 1; off < 64; off <<= 1)
        s += __shfl_xor(s, off, 64);
    __shared__ float ws[4];
    if ((threadIdx.x & 63) == 0) ws[threadIdx.x >> 6] = s;
    __syncthreads();
    if (threadIdx.x == 0) out[0] = ws[0] + ws[1] + ws[2] + ws[3];
}

extern "C" void kernel_launch(void* const* d_in, const int* in_sizes, int n_in,
                              void* d_out, int out_size, void* d_ws, size_t ws_size,
                              hipStream_t stream) {
    const float* emb      = (const float*)d_in[0];
    const int*   centers  = (const int*)d_in[1];
    const int*   contexts = (const int*)d_in[2];
    const int*   negs     = (const int*)d_in[3];
    float*       bins     = (float*)d_ws;
    float*       out      = (float*)d_out;

    const int P = in_sizes[1];
    const float invP = 1.0f / (float)P;

    // zero the partial-sum bins (64 KB) each call — d_ws is not re-poisoned
    hipMemsetAsync(d_ws, 0, NBINS * BINSTRIDE * sizeof(float), stream);

    const int block = 256;                        // 32 pairs per block
    const int grid  = (P + 31) / 32;              // exact cover: 7760 blocks
    sgns_pair_kernel<<<grid, block, 0, stream>>>(emb, centers, contexts, negs,
                                                 bins, P, invP);
    reduce_bins_kernel<<<1, 256, 0, stream>>>(bins, out);
}